// Round 16
// baseline (383.717 us; speedup 1.0000x reference)
//
#include <hip/hip_runtime.h>
#include <hip/hip_bf16.h>
#include <math.h>

#define B_ 4
#define CG_ 64
#define H_ 240
#define W_ 1216
#define NUMK 576            // 9 taps * 64 ch
#define WP (W_ + 2)         // padded gbf row stride (cols -1..W)
#define HP (H_ + 2)         // padded gbf rows (-1..H)
#define WPAD (W_ + 4)       // padded f32 plane row stride (2-px zero border)
#define HPAD (H_ + 4)
#define PPLANE ((size_t)HPAD * WPAD)   // padded plane elems per batch

// ---- conv tile: 32 cols x 8 rows, 8 waves x 1 row, 512 threads ----
#define TCC 32
#define THR 8
#define SRr 10              // staged rows  h0-1 .. h0+8
#define SCc 34              // staged cols  w0-1 .. w0+32
#define NWT2 (W_ / TCC)     // 38
#define NHT2 (H_ / THR)     // 30
#define NBLK3 (NWT2 * NHT2 * B_)   // 4560, %8==0
#define CBS2 260            // cbuf pixel stride (f32), 256 px
#define SMEM_TILE (SRr * SCc * 128)    // 43520
#define WBUF_BYTES (18 * 1024 * 2)     // 36864: ALL 18 K-steps of weight fragments
#define SMEM_BYTES (SMEM_TILE + WBUF_BYTES)   // 80384 -> 2 blocks/CU
#define NCHK (SRr * SCc * 8)           // 2720 16B staging chunks

// ---- R5 fallback tile ----
#define R5TC 16
#define R5TH 4
#define R5SC 20
#define R5SR 6
#define R5CPAD 72
#define R5NWT (W_ / R5TC)
#define R5NHT (H_ / R5TH)
#define R5NBLK (R5NWT * R5NHT * B_)
#define R5CBS 68

typedef __attribute__((ext_vector_type(8))) short bf16x8;
typedef __attribute__((ext_vector_type(4))) float f32x4;

// Bilinear with zero padding via per-corner validity (fallback path only).
__device__ __forceinline__ float bilin_zero(const float* __restrict__ img, float y, float x) {
    float y0f = floorf(y), x0f = floorf(x);
    float wy = y - y0f, wx = x - x0f;
    int y0 = (int)y0f, x0 = (int)x0f;
    int y1 = y0 + 1, x1 = x0 + 1;
    bool yv0 = ((unsigned)y0 < (unsigned)H_);
    bool yv1 = ((unsigned)y1 < (unsigned)H_);
    bool xv0 = ((unsigned)x0 < (unsigned)W_);
    bool xv1 = ((unsigned)x1 < (unsigned)W_);
    float v00 = (yv0 && xv0) ? img[y0 * W_ + x0] : 0.f;
    float v01 = (yv0 && xv1) ? img[y0 * W_ + x1] : 0.f;
    float v10 = (yv1 && xv0) ? img[y1 * W_ + x0] : 0.f;
    float v11 = (yv1 && xv1) ? img[y1 * W_ + x1] : 0.f;
    return v00 * (1.f - wy) * (1.f - wx) + v01 * (1.f - wy) * wx
         + v10 * wy * (1.f - wx) + v11 * wy * wx;
}

// Branchless bilinear on a 2-px zero-bordered plane (exact zero-pad semantics).
__device__ __forceinline__ float bilin_pad(const float* __restrict__ imgp, float y, float x) {
    float yc = fminf(fmaxf(y, -2.0f), (float)H_);
    float xc = fminf(fmaxf(x, -2.0f), (float)W_);
    float y0f = floorf(yc), x0f = floorf(xc);
    float wy = yc - y0f, wx = xc - x0f;
    int iy = (int)y0f + 2, ix = (int)x0f + 2;
    const float* p = imgp + iy * WPAD + ix;
    float v00 = p[0], v01 = p[1], v10 = p[WPAD], v11 = p[WPAD + 1];
    return v00 * (1.f - wy) * (1.f - wx) + v01 * (1.f - wy) * wx
         + v10 * wy * (1.f - wx) + v11 * wy * wx;
}

// Full single-thread epilogue (R5 fallback path only).
__device__ __forceinline__ void prep_epilogue(
    const float* a24, int b, int h, int w,
    const float* __restrict__ confidence, const float* __restrict__ feat_init,
    const float* __restrict__ feat_fix, float scale,
    float* __restrict__ out_offset, float* __restrict__ out_aff9,
    float* __restrict__ fb0, unsigned* __restrict__ offb, ushort* __restrict__ affb)
{
    const float* confb = confidence + (size_t)b * H_ * W_;
    float dyv[8], dxv[8], av[8];
    float ssum = 0.f;
    #pragma unroll
    for (int j = 0; j < 8; j++) {
        float dy = a24[j];
        float dx = a24[8 + j];
        float a = tanhf(a24[16 + j]) / scale;
        float conf = bilin_zero(confb, (float)h + dy, (float)w + dx);
        a *= conf;
        dyv[j] = dy; dxv[j] = dx; av[j] = a;
        ssum += fabsf(a);
    }
    float s = fmaxf(ssum + 1e-4f, 1.0f);
    float inv_s = 1.0f / s;
    float suma = 0.f;
    #pragma unroll
    for (int j = 0; j < 8; j++) { av[j] *= inv_s; suma += av[j]; }
    const float aref = 1.0f - suma;

    const int hw = h * W_ + w;
    #pragma unroll
    for (int k = 0; k < 9; k++) {
        float dy = (k == 4) ? 0.f : dyv[(k < 4) ? k : k - 1];
        float dx = (k == 4) ? 0.f : dxv[(k < 4) ? k : k - 1];
        float a  = (k == 4) ? aref : av[(k < 4) ? k : k - 1];
        out_offset[((size_t)(b * 18 + 2 * k) * H_) * W_ + hw] = dy;
        out_offset[((size_t)(b * 18 + 2 * k + 1) * H_) * W_ + hw] = dx;
        out_aff9[((size_t)(b * 9 + k) * H_) * W_ + hw] = a;
        if (offb) {
            __hip_bfloat16 hy = __float2bfloat16(dy);
            __hip_bfloat16 hx = __float2bfloat16(dx);
            __hip_bfloat16 ha = __float2bfloat16(a);
            unsigned uy = *(ushort*)&hy, ux = *(ushort*)&hx;
            offb[((size_t)(b * 9 + k) * H_) * W_ + hw] = uy | (ux << 16);
            affb[((size_t)(b * 9 + k) * H_) * W_ + hw] = *(ushort*)&ha;
        }
    }
    const size_t pix = (size_t)b * H_ * W_ + hw;
    float ff = feat_fix[pix];
    float fi = feat_init[pix];
    float m = (ff > 0.f) ? 1.f : 0.f;
    fb0[pix] = (1.f - m) * fi + m * ff;
}

// Init the 3 contiguous padded planes: fbp0 (zeros), fbp1 (zeros), confp (padded copy).
__global__ __launch_bounds__(256) void init_pads_kernel(
    const float* __restrict__ confidence, float* __restrict__ base)
{
    const int n = (int)(3 * B_ * PPLANE);
    int i = blockIdx.x * 256 + threadIdx.x;
    if (i >= n) return;
    float v = 0.f;
    const int cbase = (int)(2 * B_ * PPLANE);
    if (i >= cbase) {
        int local = i - cbase;
        int col = local % WPAD;
        int row = (local / WPAD) % HPAD;
        int b = local / (int)PPLANE;
        int gh = row - 2, gw = col - 2;
        if ((unsigned)gh < (unsigned)H_ && (unsigned)gw < (unsigned)W_)
            v = confidence[((size_t)b * H_ + gh) * W_ + gw];
    }
    base[i] = v;
}

// Repack conv_w [24][64][3][3] into fragment-major bf16 (wave-contiguous A loads).
__global__ __launch_bounds__(256) void repack_w_kernel(
    const float* __restrict__ conv_w, __hip_bfloat16* __restrict__ wfrag)
{
    int i = blockIdx.x * 256 + threadIdx.x;
    if (i >= 32 * NUMK) return;
    int e = i & 7;
    int p = (i >> 3) & 15;
    int g = (i >> 7) & 3;
    int half = (i >> 9) & 1;
    int s = i >> 10;
    int m = half * 16 + p;
    int kp = s * 32 + g * 8 + e;
    int tap = kp / 64, c = kp % 64;
    float v = (m < 24) ? conv_w[m * NUMK + c * 9 + tap] : 0.f;
    wfrag[i] = __float2bfloat16(v);
}

// Transpose+convert guidance [B][64][H][W] f32 -> gbf [B][HP][WP][64] bf16,
// PRE-SWIZZLED: within each column's 128 B channel row, the 16 B chunk at
// semantic byte z is stored at z ^ ((gc & 7) << 4), gc = gbf column index.
// (Conv's K-loop read applies the same XOR, so gload_lds can copy linearly.)
__global__ __launch_bounds__(256) void transpose_kernel(
    const float* __restrict__ guidance, __hip_bfloat16* __restrict__ gbf)
{
    __shared__ __align__(16) __hip_bfloat16 tl[64 * 72];   // [col][ch]
    const int tid = threadIdx.x;
    const int w0 = blockIdx.x * 64;
    const int row = blockIdx.y;           // gbf row 0..HP-1
    const int b = blockIdx.z;
    const int gh = row - 1;
    __hip_bfloat16* gbfb = gbf + (size_t)b * HP * WP * 64;

    const int px = tid >> 2;
    const int ch0 = (tid & 3) * 16;
    const int gc = 1 + w0 + px;           // gbf column (w0 % 8 == 0 -> gc&7 = (px+1)&7)
    const int xorv = (gc & 7) << 4;
    bf16x8 z8 = {};

    char* rowbase = (char*)(gbfb + ((size_t)row * WP + gc) * 64);
    const int b0 = ch0 * 2;               // semantic byte offset (0,32,64,96)

    if ((unsigned)gh < (unsigned)H_) {
        const int col = tid & 63;
        const int chb = tid >> 6;
        #pragma unroll
        for (int r = 0; r < 16; r++) {
            int ch = r * 4 + chb;
            float v = guidance[(((size_t)b * CG_ + ch) * H_ + gh) * W_ + w0 + col];
            tl[col * 72 + ch] = __float2bfloat16(v);
        }
        __syncthreads();
        *(bf16x8*)(rowbase + (b0 ^ xorv)) = *(const bf16x8*)&tl[px * 72 + ch0];
        *(bf16x8*)(rowbase + ((b0 + 16) ^ xorv)) = *(const bf16x8*)&tl[px * 72 + ch0 + 8];
    } else {
        *(bf16x8*)(rowbase + (b0 ^ xorv)) = z8;
        *(bf16x8*)(rowbase + ((b0 + 16) ^ xorv)) = z8;
    }
    // pad columns: all-zero 128 B rows; chunk permutation is coverage-invariant.
    if (blockIdx.x == 0 && tid < 8)
        *(bf16x8*)(gbfb + ((size_t)row * WP) * 64 + tid * 8) = z8;
    if (blockIdx.x == 18 && tid < 8)
        *(bf16x8*)(gbfb + ((size_t)row * WP + WP - 1) * 64 + tid * 8) = z8;
}

// LDS-staged implicit-GEMM conv from pre-swizzled gbf + pair-split prep epilogue.
// Staging via global_load_lds (linear dest; swizzle baked into gbf).
__global__ __launch_bounds__(512, 4) void conv_lds_kernel(
    const __hip_bfloat16* __restrict__ gbf, const __hip_bfloat16* __restrict__ wfrag,
    const float* __restrict__ conv_b, const float* __restrict__ confp,
    const float* __restrict__ feat_init, const float* __restrict__ feat_fix,
    const float* __restrict__ aff_scale,
    float* __restrict__ out_offset, float* __restrict__ out_aff9,
    float* __restrict__ fbp0, unsigned* __restrict__ offb, ushort* __restrict__ affb)
{
    __shared__ __align__(16) char smem[SMEM_BYTES];   // tile | wbuf ; tile reused as cbuf
    __hip_bfloat16* wlds = (__hip_bfloat16*)(smem + SMEM_TILE);

    const int tid = threadIdx.x;
    int lin = (blockIdx.x & 7) * (NBLK3 / 8) + (blockIdx.x >> 3);
    const int r0 = lin % NHT2;          // row-tile fastest -> vertical strips per XCD
    const int rest = lin / NHT2;
    const int wt = rest % NWT2;
    const int b  = rest / NWT2;
    const int h0 = r0 * THR;
    const int w0 = wt * TCC;

    const int lane = tid & 63;
    const int wvbase = tid - lane;        // wave-uniform thread base

    // ---- tile staging: linear copy of 10 rows x 4352 B via global_load_lds ----
    {
        const char* gsrc = (const char*)gbf + (size_t)b * HP * WP * 128;
        auto g_of = [&](int i) -> const char* {
            int r = i / (SCc * 8);
            int c16 = i % (SCc * 8);
            return gsrc + ((size_t)(h0 + r) * WP + w0) * 128 + (size_t)c16 * 16;
        };
        #pragma unroll
        for (int it = 0; it < 5; it++) {
            int i = tid + it * 512;
            __builtin_amdgcn_global_load_lds(
                (const unsigned int*)g_of(i),
                (unsigned int*)(smem + (size_t)(wvbase + it * 512) * 16), 16, 0, 0);
        }
        if (tid < 128) {                  // chunks 2560..2687 (2 full waves)
            int i = tid + 2560;
            __builtin_amdgcn_global_load_lds(
                (const unsigned int*)g_of(i),
                (unsigned int*)(smem + (size_t)(wvbase + 2560) * 16), 16, 0, 0);
        }
        if (tid < 32) {                   // chunks 2688..2719 (reg tail, partial wave)
            int i = tid + 2688;
            *(bf16x8*)(smem + (size_t)i * 16) = *(const bf16x8*)g_of(i);
        }
    }
    // ---- weight staging: 2304 chunks, all full-wave global_load_lds ----
    {
        const char* wsrc = (const char*)wfrag;
        #pragma unroll
        for (int it = 0; it < 4; it++) {
            int i = tid + it * 512;
            __builtin_amdgcn_global_load_lds(
                (const unsigned int*)(wsrc + (size_t)i * 16),
                (unsigned int*)((char*)wlds + (size_t)(wvbase + it * 512) * 16), 16, 0, 0);
        }
        if (tid < 256) {                  // chunks 2048..2303 (4 full waves)
            int i = tid + 2048;
            __builtin_amdgcn_global_load_lds(
                (const unsigned int*)(wsrc + (size_t)i * 16),
                (unsigned int*)((char*)wlds + (size_t)(wvbase + 2048) * 16), 16, 0, 0);
        }
    }
    __syncthreads();

    // ---- MFMA K-loop: 18 barrier-free steps (weights + tile from LDS) ----
    const int wid  = tid >> 6;            // wave -> row h0+wid (0..7)
    const int p    = lane & 15;
    const int g    = lane >> 4;

    f32x4 acc[2][2] = {};                 // [Mtile][colhalf]

    #pragma unroll
    for (int s = 0; s < 18; s++) {
        const int tap = s >> 1;
        const int ky = tap / 3, kx = tap % 3;
        const int c0b = (s & 1) * 64;     // channel-half byte offset
        const __hip_bfloat16* wp = wlds + (size_t)s * 1024 + g * 128 + p * 8;
        bf16x8 a0 = *(const bf16x8*)(wp);
        bf16x8 a1 = *(const bf16x8*)(wp + 512);
        const int srow = wid + ky;
        #pragma unroll
        for (int nf = 0; nf < 2; nf++) {
            int scol = nf * 16 + p + kx;
            int off = (srow * SCc + scol) * 128 + ((c0b + g * 16) ^ ((scol & 7) << 4));
            bf16x8 bv = *(const bf16x8*)(smem + off);
            acc[0][nf] = __builtin_amdgcn_mfma_f32_16x16x32_bf16(a0, bv, acc[0][nf], 0, 0, 0);
            acc[1][nf] = __builtin_amdgcn_mfma_f32_16x16x32_bf16(a1, bv, acc[1][nf], 0, 0, 0);
        }
    }
    __syncthreads();

    // ---- spill: cbuf[ch][px], px = wid*32 + nf*16 + p (0..255) ----
    float* cbuf = (float*)smem;
    #pragma unroll
    for (int mt = 0; mt < 2; mt++) {
        int ch = mt * 16 + g * 4;
        if (ch < 24) {
            #pragma unroll
            for (int nf = 0; nf < 2; nf++) {
                int px = wid * 32 + nf * 16 + p;
                #pragma unroll
                for (int r = 0; r < 4; r++)
                    cbuf[(size_t)(ch + r) * CBS2 + px] = acc[mt][nf][r];
            }
        }
    }
    __syncthreads();

    // ---- pair-split epilogue: thread pair (2i,2i+1) shares pixel i (0..255) ----
    {
        const int pxid = tid >> 1;        // 0..255
        const int sub = tid & 1;          // 0: taps j=0..3, k=0..4, fb0; 1: j=4..7, k=5..8
        const int h = h0 + (pxid >> 5);
        const int w = w0 + (pxid & 31);
        const float scale = aff_scale[0] + 1e-8f;
        const float* confb = confp + (size_t)b * PPLANE;

        float dyv[4], dxv[4], av[4];
        float part = 0.f;
        #pragma unroll
        for (int jj = 0; jj < 4; jj++) {
            int j = sub * 4 + jj;
            float dy = cbuf[(size_t)j * CBS2 + pxid] + conv_b[j];
            float dx = cbuf[(size_t)(8 + j) * CBS2 + pxid] + conv_b[8 + j];
            float a = tanhf(cbuf[(size_t)(16 + j) * CBS2 + pxid] + conv_b[16 + j]) / scale;
            float conf = bilin_pad(confb, (float)h + dy, (float)w + dx);
            a *= conf;
            dyv[jj] = dy; dxv[jj] = dx; av[jj] = a;
            part += fabsf(a);
        }
        float ssum = part + __shfl_xor(part, 1);
        float s = fmaxf(ssum + 1e-4f, 1.0f);
        float inv_s = 1.0f / s;
        float sp = 0.f;
        #pragma unroll
        for (int jj = 0; jj < 4; jj++) { av[jj] *= inv_s; sp += av[jj]; }
        float suma = sp + __shfl_xor(sp, 1);

        const int hw = h * W_ + w;
        auto store_k = [&](int k, float dy, float dx, float a) {
            out_offset[((size_t)(b * 18 + 2 * k) * H_) * W_ + hw] = dy;
            out_offset[((size_t)(b * 18 + 2 * k + 1) * H_) * W_ + hw] = dx;
            out_aff9[((size_t)(b * 9 + k) * H_) * W_ + hw] = a;
            __hip_bfloat16 hy = __float2bfloat16(dy);
            __hip_bfloat16 hx = __float2bfloat16(dx);
            __hip_bfloat16 ha = __float2bfloat16(a);
            unsigned uy = *(ushort*)&hy, ux = *(ushort*)&hx;
            offb[((size_t)(b * 9 + k) * H_) * W_ + hw] = uy | (ux << 16);
            affb[((size_t)(b * 9 + k) * H_) * W_ + hw] = *(ushort*)&ha;
        };
        if (sub == 0) {
            #pragma unroll
            for (int jj = 0; jj < 4; jj++)
                store_k(jj, dyv[jj], dxv[jj], av[jj]);           // k=0..3 (j=k)
            store_k(4, 0.f, 0.f, 1.0f - suma);                    // center
            const size_t pix = (size_t)b * H_ * W_ + hw;
            float ff = feat_fix[pix];
            float fi = feat_init[pix];
            float m = (ff > 0.f) ? 1.f : 0.f;
            fbp0[(size_t)b * PPLANE + (size_t)(h + 2) * WPAD + (w + 2)] =
                (1.f - m) * fi + m * ff;
        } else {
            #pragma unroll
            for (int jj = 0; jj < 4; jj++)
                store_k(5 + jj, dyv[jj], dxv[jj], av[jj]);       // k=5..8 (j=k-1)
        }
    }
}

// Propagation step, 2 pixels per thread, padded fb input, branchless gathers.
// Center tap (k=4) has dy=dx=0 by construction -> exact direct read, no offb load.
__global__ __launch_bounds__(256) void prop_packed_kernel(
    const float* __restrict__ fbp_in, const unsigned* __restrict__ offb,
    const ushort* __restrict__ affb, const float* __restrict__ feat_fix,
    float* __restrict__ out, int do_blend, int out_padded)
{
    const int tpx = blockIdx.x * 256 + threadIdx.x;
    const int n2 = (B_ * H_ * W_) / 2;
    if (tpx >= n2) return;
    const int idx = tpx * 2;
    const int w = idx % W_;
    const int h = (idx / W_) % H_;
    const int b = idx / (W_ * H_);
    const float* fbb = fbp_in + (size_t)b * PPLANE;
    const int hw = h * W_ + w;

    float sum0 = 0.f, sum1 = 0.f;
    #pragma unroll
    for (int k = 0; k < 9; k++) {
        const size_t pb = ((size_t)(b * 9 + k) * H_) * W_ + hw;
        unsigned ua = *(const unsigned*)(affb + pb);
        float a0  = __uint_as_float(ua << 16);
        float a1  = __uint_as_float(ua & 0xFFFF0000u);
        if (k == 4) {
            const float* c = fbb + (size_t)(h + 2) * WPAD + (w + 2);
            sum0 += a0 * c[0];
            sum1 += a1 * c[1];
        } else {
            uint2 uo = *(const uint2*)(offb + pb);
            float yb = (float)h + (float)(k / 3 - 1);
            float xb = (float)w + (float)(k % 3 - 1);
            float dy0 = __uint_as_float(uo.x << 16);
            float dx0 = __uint_as_float(uo.x & 0xFFFF0000u);
            sum0 += a0 * bilin_pad(fbb, yb + dy0, xb + dx0);
            float dy1 = __uint_as_float(uo.y << 16);
            float dx1 = __uint_as_float(uo.y & 0xFFFF0000u);
            sum1 += a1 * bilin_pad(fbb, yb + dy1, xb + 1.0f + dx1);
        }
    }
    if (do_blend) {
        float2 ff = *(const float2*)(feat_fix + idx);
        if (ff.x > 0.f) sum0 = ff.x;
        if (ff.y > 0.f) sum1 = ff.y;
    }
    if (out_padded) {
        float* o = out + (size_t)b * PPLANE + (size_t)(h + 2) * WPAD + (w + 2);
        *(float2*)o = make_float2(sum0, sum1);
    } else {
        *(float2*)(out + idx) = make_float2(sum0, sum1);
    }
}

// ---------------- R5 fallback path (used only if ws_size too small) ----------------
__global__ __launch_bounds__(256, 8) void conv_mfma_r5(
    const float* __restrict__ guidance, const __hip_bfloat16* __restrict__ wfrag,
    const float* __restrict__ conv_b, const float* __restrict__ confidence,
    const float* __restrict__ feat_init, const float* __restrict__ feat_fix,
    const float* __restrict__ aff_scale,
    float* __restrict__ out_offset, float* __restrict__ out_aff9,
    float* __restrict__ fb0)
{
    __shared__ __align__(16) __hip_bfloat16 gl[R5SR * R5SC * R5CPAD];
    const int tid = threadIdx.x;
    int lin = (blockIdx.x & 7) * (R5NBLK / 8) + (blockIdx.x >> 3);
    const int r0 = lin % R5NHT;
    const int rest = lin / R5NHT;
    const int wt = rest % R5NWT;
    const int b  = rest / R5NWT;
    const int h0 = r0 * R5TH;
    const int w0 = wt * R5TC;
    {
        auto stage_one = [&](int i) {
            int col = i % R5SC;
            int rest2 = i / R5SC;
            int kr = rest2 % R5SR;
            int c4 = rest2 / R5SR;
            int gh = h0 - 1 + kr;
            int gw = w0 - 2 + col;
            bool vok = ((unsigned)gh < (unsigned)H_) & ((unsigned)gw < (unsigned)W_);
            union { unsigned long long u; __hip_bfloat16 hv[4]; } pk;
            const float* src = guidance + (((size_t)b * CG_ + c4 * 4) * H_ + gh) * W_ + gw;
            #pragma unroll
            for (int j = 0; j < 4; j++) {
                float v = vok ? src[(size_t)j * H_ * W_] : 0.f;
                pk.hv[j] = __float2bfloat16(v);
            }
            *(unsigned long long*)&gl[(size_t)(kr * R5SC + col) * R5CPAD + c4 * 4] = pk.u;
        };
        #pragma unroll
        for (int it = 0; it < 7; it++) stage_one(tid + it * 256);
        if (tid < R5SR * R5SC * 16 - 7 * 256) stage_one(tid + 7 * 256);
    }
    __syncthreads();
    const int lane = tid & 63;
    const int wid  = tid >> 6;
    const int p    = lane & 15;
    const int g    = lane >> 4;
    f32x4 acc[2] = {};
    #pragma unroll
    for (int s = 0; s < 18; s++) {
        const int tap = s >> 1;
        const int ky = tap / 3, kx = tap % 3;
        const int c0 = (s & 1) * 32;
        const __hip_bfloat16* wp = wfrag + (size_t)s * 1024 + g * 128 + p * 8;
        bf16x8 a0 = *(const bf16x8*)(wp);
        bf16x8 a1 = *(const bf16x8*)(wp + 512);
        int cb = p + kx + 1;
        bf16x8 b0 = *(const bf16x8*)(gl + (size_t)((wid + ky) * R5SC + cb) * R5CPAD + c0 + g * 8);
        acc[0] = __builtin_amdgcn_mfma_f32_16x16x32_bf16(a0, b0, acc[0], 0, 0, 0);
        acc[1] = __builtin_amdgcn_mfma_f32_16x16x32_bf16(a1, b0, acc[1], 0, 0, 0);
    }
    __syncthreads();
    float* cbuf = (float*)gl;
    #pragma unroll
    for (int mt = 0; mt < 2; mt++) {
        int ch = mt * 16 + g * 4;
        if (ch < 24) {
            int px = wid * 16 + p;
            #pragma unroll
            for (int r = 0; r < 4; r++)
                cbuf[(size_t)(ch + r) * R5CBS + px] = acc[mt][r];
        }
    }
    __syncthreads();
    if (tid < R5TH * R5TC) {
        const int h = h0 + (tid >> 4);
        const int w = w0 + (tid & 15);
        float a24[24];
        #pragma unroll
        for (int ch = 0; ch < 24; ch++)
            a24[ch] = cbuf[(size_t)ch * R5CBS + tid] + conv_b[ch];
        prep_epilogue(a24, b, h, w, confidence, feat_init, feat_fix,
                      aff_scale[0] + 1e-8f, out_offset, out_aff9, fb0,
                      (unsigned*)nullptr, (ushort*)nullptr);
    }
}

__global__ __launch_bounds__(256) void prop_f32_kernel(
    const float* __restrict__ fb_in, const float* __restrict__ offset,
    const float* __restrict__ aff9, const float* __restrict__ feat_fix,
    float* __restrict__ out, int do_blend)
{
    const int idx = blockIdx.x * 256 + threadIdx.x;
    const int n = B_ * H_ * W_;
    if (idx >= n) return;
    const int w = idx % W_;
    const int h = (idx / W_) % H_;
    const int b = idx / (W_ * H_);
    const float* fbb = fb_in + (size_t)b * H_ * W_;
    const int hw = h * W_ + w;
    float sum = 0.f;
    #pragma unroll
    for (int k = 0; k < 9; k++) {
        float dy = offset[((size_t)(b * 18 + 2 * k) * H_) * W_ + hw];
        float dx = offset[((size_t)(b * 18 + 2 * k + 1) * H_) * W_ + hw];
        float a  = aff9[((size_t)(b * 9 + k) * H_) * W_ + hw];
        float y = (float)h + (float)(k / 3 - 1) + dy;
        float x = (float)w + (float)(k % 3 - 1) + dx;
        sum += a * bilin_zero(fbb, y, x);
    }
    if (do_blend) {
        float ff = feat_fix[idx];
        float m = (ff > 0.f) ? 1.f : 0.f;
        sum = (1.f - m) * sum + m * ff;
    }
    out[idx] = sum;
}

extern "C" void kernel_launch(void* const* d_in, const int* in_sizes, int n_in,
                              void* d_out, int out_size, void* d_ws, size_t ws_size,
                              hipStream_t stream) {
    const float* feat_init  = (const float*)d_in[0];
    const float* guidance   = (const float*)d_in[1];
    const float* confidence = (const float*)d_in[2];
    const float* feat_fix   = (const float*)d_in[3];
    const float* conv_w     = (const float*)d_in[4];
    const float* conv_b     = (const float*)d_in[5];
    const float* aff_scale  = (const float*)d_in[6];

    float* out_feat = (float*)d_out;
    const size_t P1 = (size_t)B_ * H_ * W_;
    float* out_offset = out_feat + P1;
    float* out_aff9   = out_offset + 18 * P1;

    char* ws = (char*)d_ws;
    float* fb0 = (float*)ws;                                   ws += P1 * 4;   // fallback only
    float* fb1 = (float*)ws;                                   ws += P1 * 4;   // fallback only
    __hip_bfloat16* wfrag = (__hip_bfloat16*)ws;               ws += 32 * NUMK * 2;
    unsigned* offb = (unsigned*)ws;                            ws += 9 * P1 * 4;
    ushort* affb = (ushort*)ws;                                ws += 9 * P1 * 2;
    __hip_bfloat16* gbf = (__hip_bfloat16*)ws;                 ws += (size_t)B_ * HP * WP * 64 * 2;
    float* fbp0 = (float*)ws;                                  ws += B_ * PPLANE * 4;
    float* fbp1 = (float*)ws;                                  ws += B_ * PPLANE * 4;
    float* confp = (float*)ws;                                 ws += B_ * PPLANE * 4;
    const size_t need = (size_t)(ws - (char*)d_ws);

    repack_w_kernel<<<(32 * NUMK + 255) / 256, 256, 0, stream>>>(conv_w, wfrag);

    const int n = (int)P1;

    if (ws_size >= need) {
        const int ni = (int)(3 * B_ * PPLANE);
        init_pads_kernel<<<(ni + 255) / 256, 256, 0, stream>>>(confidence, fbp0);
        transpose_kernel<<<dim3(19, HP, B_), 256, 0, stream>>>(guidance, gbf);
        conv_lds_kernel<<<NBLK3, 512, 0, stream>>>(
            gbf, wfrag, conv_b, confp, feat_init, feat_fix, aff_scale,
            out_offset, out_aff9, fbp0, offb, affb);
        const int p2blocks = (n / 2 + 255) / 256;
        float* pbufs[2] = {fbp0, fbp1};
        for (int it = 0; it < 6; it++) {
            const float* in = pbufs[it & 1];
            float* o = (it == 5) ? out_feat : pbufs[(it + 1) & 1];
            prop_packed_kernel<<<p2blocks, 256, 0, stream>>>(
                in, offb, affb, feat_fix, o, (it < 5) ? 1 : 0, (it < 5) ? 1 : 0);
        }
    } else {
        const int pblocks = (n + 255) / 256;
        float* bufs[2] = {fb0, fb1};
        conv_mfma_r5<<<R5NBLK, 256, 0, stream>>>(
            guidance, wfrag, conv_b, confidence, feat_init, feat_fix, aff_scale,
            out_offset, out_aff9, fb0);
        for (int it = 0; it < 6; it++) {
            const float* in = bufs[it & 1];
            float* o = (it == 5) ? out_feat : bufs[(it + 1) & 1];
            prop_f32_kernel<<<pblocks, 256, 0, stream>>>(
                in, out_offset, out_aff9, feat_fix, o, (it < 5) ? 1 : 0);
        }
    }
}

// Round 17
// 373.818 us; speedup vs baseline: 1.0265x; 1.0265x over previous
//
#include <hip/hip_runtime.h>
#include <hip/hip_bf16.h>
#include <math.h>

#define B_ 4
#define CG_ 64
#define H_ 240
#define W_ 1216
#define NUMK 576            // 9 taps * 64 ch
#define WP (W_ + 2)         // padded gbf row stride (cols -1..W)
#define HP (H_ + 2)         // padded gbf rows (-1..H)
#define WPAD (W_ + 4)       // padded f32 plane row stride (2-px zero border)
#define HPAD (H_ + 4)
#define PPLANE ((size_t)HPAD * WPAD)   // padded plane elems per batch

// ---- conv tile: 32 cols x 8 rows, 8 waves x 1 row, 512 threads ----
#define TCC 32
#define THR 8
#define SRr 10              // staged rows  h0-1 .. h0+8
#define SCc 34              // staged cols  w0-1 .. w0+32
#define NWT2 (W_ / TCC)     // 38
#define NHT2 (H_ / THR)     // 30
#define NBLK3 (NWT2 * NHT2 * B_)   // 4560, %8==0
#define CBS2 260            // cbuf pixel stride (f32), 256 px
#define SMEM_TILE (SRr * SCc * 128)    // 43520
#define WBUF_BYTES (18 * 1024 * 2)     // 36864: ALL 18 K-steps of weight fragments
#define SMEM_BYTES (SMEM_TILE + WBUF_BYTES)   // 80384 -> 2 blocks/CU
#define NCHK (SRr * SCc * 8)           // 2720 16B staging chunks

// border-only init: per plane, 4 full rows + 4 edge cols of middle rows
#define BORD_A (4 * WPAD)                  // 4880
#define BORD_B ((HPAD - 4) * 4)            // 960
#define BORD_PER (BORD_A + BORD_B)         // 5840
#define BORD_TOTAL (8 * BORD_PER)          // 2 bufs x 4 batches

// ---- R5 fallback tile ----
#define R5TC 16
#define R5TH 4
#define R5SC 20
#define R5SR 6
#define R5CPAD 72
#define R5NWT (W_ / R5TC)
#define R5NHT (H_ / R5TH)
#define R5NBLK (R5NWT * R5NHT * B_)
#define R5CBS 68

typedef __attribute__((ext_vector_type(8))) short bf16x8;
typedef __attribute__((ext_vector_type(4))) float f32x4;

// Bilinear with zero padding via per-corner validity (fallback path only).
__device__ __forceinline__ float bilin_zero(const float* __restrict__ img, float y, float x) {
    float y0f = floorf(y), x0f = floorf(x);
    float wy = y - y0f, wx = x - x0f;
    int y0 = (int)y0f, x0 = (int)x0f;
    int y1 = y0 + 1, x1 = x0 + 1;
    bool yv0 = ((unsigned)y0 < (unsigned)H_);
    bool yv1 = ((unsigned)y1 < (unsigned)H_);
    bool xv0 = ((unsigned)x0 < (unsigned)W_);
    bool xv1 = ((unsigned)x1 < (unsigned)W_);
    float v00 = (yv0 && xv0) ? img[y0 * W_ + x0] : 0.f;
    float v01 = (yv0 && xv1) ? img[y0 * W_ + x1] : 0.f;
    float v10 = (yv1 && xv0) ? img[y1 * W_ + x0] : 0.f;
    float v11 = (yv1 && xv1) ? img[y1 * W_ + x1] : 0.f;
    return v00 * (1.f - wy) * (1.f - wx) + v01 * (1.f - wy) * wx
         + v10 * wy * (1.f - wx) + v11 * wy * wx;
}

// Branchless bilinear on a 2-px zero-bordered plane (exact zero-pad semantics).
__device__ __forceinline__ float bilin_pad(const float* __restrict__ imgp, float y, float x) {
    float yc = fminf(fmaxf(y, -2.0f), (float)H_);
    float xc = fminf(fmaxf(x, -2.0f), (float)W_);
    float y0f = floorf(yc), x0f = floorf(xc);
    float wy = yc - y0f, wx = xc - x0f;
    int iy = (int)y0f + 2, ix = (int)x0f + 2;
    const float* p = imgp + iy * WPAD + ix;
    float v00 = p[0], v01 = p[1], v10 = p[WPAD], v11 = p[WPAD + 1];
    return v00 * (1.f - wy) * (1.f - wx) + v01 * (1.f - wy) * wx
         + v10 * wy * (1.f - wx) + v11 * wy * wx;
}

// Full single-thread epilogue (R5 fallback path only).
__device__ __forceinline__ void prep_epilogue(
    const float* a24, int b, int h, int w,
    const float* __restrict__ confidence, const float* __restrict__ feat_init,
    const float* __restrict__ feat_fix, float scale,
    float* __restrict__ out_offset, float* __restrict__ out_aff9,
    float* __restrict__ fb0, unsigned* __restrict__ offb, ushort* __restrict__ affb)
{
    const float* confb = confidence + (size_t)b * H_ * W_;
    float dyv[8], dxv[8], av[8];
    float ssum = 0.f;
    #pragma unroll
    for (int j = 0; j < 8; j++) {
        float dy = a24[j];
        float dx = a24[8 + j];
        float a = tanhf(a24[16 + j]) / scale;
        float conf = bilin_zero(confb, (float)h + dy, (float)w + dx);
        a *= conf;
        dyv[j] = dy; dxv[j] = dx; av[j] = a;
        ssum += fabsf(a);
    }
    float s = fmaxf(ssum + 1e-4f, 1.0f);
    float inv_s = 1.0f / s;
    float suma = 0.f;
    #pragma unroll
    for (int j = 0; j < 8; j++) { av[j] *= inv_s; suma += av[j]; }
    const float aref = 1.0f - suma;

    const int hw = h * W_ + w;
    #pragma unroll
    for (int k = 0; k < 9; k++) {
        float dy = (k == 4) ? 0.f : dyv[(k < 4) ? k : k - 1];
        float dx = (k == 4) ? 0.f : dxv[(k < 4) ? k : k - 1];
        float a  = (k == 4) ? aref : av[(k < 4) ? k : k - 1];
        out_offset[((size_t)(b * 18 + 2 * k) * H_) * W_ + hw] = dy;
        out_offset[((size_t)(b * 18 + 2 * k + 1) * H_) * W_ + hw] = dx;
        out_aff9[((size_t)(b * 9 + k) * H_) * W_ + hw] = a;
        if (offb) {
            __hip_bfloat16 hy = __float2bfloat16(dy);
            __hip_bfloat16 hx = __float2bfloat16(dx);
            __hip_bfloat16 ha = __float2bfloat16(a);
            unsigned uy = *(ushort*)&hy, ux = *(ushort*)&hx;
            offb[((size_t)(b * 9 + k) * H_) * W_ + hw] = uy | (ux << 16);
            affb[((size_t)(b * 9 + k) * H_) * W_ + hw] = *(ushort*)&ha;
        }
    }
    const size_t pix = (size_t)b * H_ * W_ + hw;
    float ff = feat_fix[pix];
    float fi = feat_init[pix];
    float m = (ff > 0.f) ? 1.f : 0.f;
    fb0[pix] = (1.f - m) * fi + m * ff;
}

// Border-only init of fbp0/fbp1 (interiors are fully rewritten every launch:
// fbp0 by conv's epilogue, fbp1 by prop iter 0) + full padded conf copy.
__global__ __launch_bounds__(256) void init_pads_kernel(
    const float* __restrict__ confidence, float* __restrict__ base)
{
    const int nconf = (int)(B_ * PPLANE);
    const int n = BORD_TOTAL + nconf;
    int i = blockIdx.x * 256 + threadIdx.x;
    if (i >= n) return;
    if (i < BORD_TOTAL) {
        int pl = i / BORD_PER;            // plane index (buf*4 + batch), planes contiguous
        int e = i % BORD_PER;
        int row, col;
        if (e < BORD_A) {
            int r4 = e / WPAD;
            row = (r4 < 2) ? r4 : (HPAD - 4 + r4);
            col = e % WPAD;
        } else {
            int b2 = e - BORD_A;
            row = 2 + (b2 >> 2);
            int c4 = b2 & 3;
            col = (c4 < 2) ? c4 : (WPAD - 4 + c4);
        }
        base[(size_t)pl * PPLANE + (size_t)row * WPAD + col] = 0.f;
    } else {
        int local = i - BORD_TOTAL;
        int col = local % WPAD;
        int row = (local / WPAD) % HPAD;
        int b = local / (int)PPLANE;
        int gh = row - 2, gw = col - 2;
        float v = 0.f;
        if ((unsigned)gh < (unsigned)H_ && (unsigned)gw < (unsigned)W_)
            v = confidence[((size_t)b * H_ + gh) * W_ + gw];
        base[(size_t)(2 * B_) * PPLANE + local] = v;   // confp follows fbp0,fbp1
    }
}

// Repack conv_w [24][64][3][3] into fragment-major bf16 (wave-contiguous A loads).
__global__ __launch_bounds__(256) void repack_w_kernel(
    const float* __restrict__ conv_w, __hip_bfloat16* __restrict__ wfrag)
{
    int i = blockIdx.x * 256 + threadIdx.x;
    if (i >= 32 * NUMK) return;
    int e = i & 7;
    int p = (i >> 3) & 15;
    int g = (i >> 7) & 3;
    int half = (i >> 9) & 1;
    int s = i >> 10;
    int m = half * 16 + p;
    int kp = s * 32 + g * 8 + e;
    int tap = kp / 64, c = kp % 64;
    float v = (m < 24) ? conv_w[m * NUMK + c * 9 + tap] : 0.f;
    wfrag[i] = __float2bfloat16(v);
}

// Transpose+convert guidance [B][64][H][W] f32 -> gbf [B][HP][WP][64] bf16.
__global__ __launch_bounds__(256) void transpose_kernel(
    const float* __restrict__ guidance, __hip_bfloat16* __restrict__ gbf)
{
    __shared__ __align__(16) __hip_bfloat16 tl[64 * 72];   // [col][ch]
    const int tid = threadIdx.x;
    const int w0 = blockIdx.x * 64;
    const int row = blockIdx.y;           // gbf row 0..HP-1
    const int b = blockIdx.z;
    const int gh = row - 1;
    __hip_bfloat16* gbfb = gbf + (size_t)b * HP * WP * 64;

    const int px = tid >> 2;
    const int ch0 = (tid & 3) * 16;
    bf16x8 z8 = {};

    if ((unsigned)gh < (unsigned)H_) {
        const int col = tid & 63;
        const int chb = tid >> 6;
        #pragma unroll
        for (int r = 0; r < 16; r++) {
            int ch = r * 4 + chb;
            float v = guidance[(((size_t)b * CG_ + ch) * H_ + gh) * W_ + w0 + col];
            tl[col * 72 + ch] = __float2bfloat16(v);
        }
        __syncthreads();
        __hip_bfloat16* dst = gbfb + ((size_t)row * WP + 1 + w0 + px) * 64 + ch0;
        *(bf16x8*)dst = *(const bf16x8*)&tl[px * 72 + ch0];
        *(bf16x8*)(dst + 8) = *(const bf16x8*)&tl[px * 72 + ch0 + 8];
    } else {
        __hip_bfloat16* dst = gbfb + ((size_t)row * WP + 1 + w0 + px) * 64 + ch0;
        *(bf16x8*)dst = z8;
        *(bf16x8*)(dst + 8) = z8;
    }
    if (blockIdx.x == 0 && tid < 8)
        *(bf16x8*)(gbfb + ((size_t)row * WP) * 64 + tid * 8) = z8;
    if (blockIdx.x == 18 && tid < 8)
        *(bf16x8*)(gbfb + ((size_t)row * WP + WP - 1) * 64 + tid * 8) = z8;
}

// LDS-staged implicit-GEMM conv from gbf + pair-split prep epilogue.
// 32x8 tile, 512 threads. ALL weight fragments staged in LDS upfront
// (36.9 KB wbuf; barrier-free 18-step K-loop; 2 blocks/CU). (R15 verified.)
__global__ __launch_bounds__(512, 4) void conv_lds_kernel(
    const __hip_bfloat16* __restrict__ gbf, const __hip_bfloat16* __restrict__ wfrag,
    const float* __restrict__ conv_b, const float* __restrict__ confp,
    const float* __restrict__ feat_init, const float* __restrict__ feat_fix,
    const float* __restrict__ aff_scale,
    float* __restrict__ out_offset, float* __restrict__ out_aff9,
    float* __restrict__ fbp0, unsigned* __restrict__ offb, ushort* __restrict__ affb)
{
    __shared__ __align__(16) char smem[SMEM_BYTES];   // tile | wbuf ; tile reused as cbuf
    __hip_bfloat16* wlds = (__hip_bfloat16*)(smem + SMEM_TILE);

    const int tid = threadIdx.x;
    int lin = (blockIdx.x & 7) * (NBLK3 / 8) + (blockIdx.x >> 3);
    const int r0 = lin % NHT2;          // row-tile fastest -> vertical strips per XCD
    const int rest = lin / NHT2;
    const int wt = rest % NWT2;
    const int b  = rest / NWT2;
    const int h0 = r0 * THR;
    const int w0 = wt * TCC;

    // ---- stage [SRr][SCc][64ch]; contiguous 16B chunks, XOR-swizzled dest ----
    {
        const __hip_bfloat16* gsrc = gbf + (size_t)b * HP * WP * 64;
        auto stage_one = [&](int i) {
            int r = i / (SCc * 8);
            int t = i % (SCc * 8);
            int col = t >> 3;
            int chb = t & 7;
            bf16x8 v = *(const bf16x8*)(gsrc + ((size_t)(h0 + r) * WP + w0 + col) * 64 + chb * 8);
            int dst = (r * SCc + col) * 128 + ((chb * 16) ^ ((col & 7) << 4));
            *(bf16x8*)(smem + dst) = v;
        };
        #pragma unroll
        for (int it = 0; it < 5; it++)
            stage_one(tid + it * 512);
        if (tid < NCHK - 5 * 512)
            stage_one(tid + 5 * 512);
    }
    // ---- stage ALL weights: 18 steps x 1024 elems = 2304 16B chunks ----
    {
        #pragma unroll
        for (int it = 0; it < 4; it++) {
            int i = tid + it * 512;
            *(bf16x8*)(wlds + (size_t)i * 8) = *(const bf16x8*)(wfrag + (size_t)i * 8);
        }
        if (tid < 256) {
            int i = tid + 2048;
            *(bf16x8*)(wlds + (size_t)i * 8) = *(const bf16x8*)(wfrag + (size_t)i * 8);
        }
    }
    __syncthreads();

    // ---- MFMA K-loop: 18 barrier-free steps (weights + tile from LDS) ----
    const int lane = tid & 63;
    const int wid  = tid >> 6;            // wave -> row h0+wid (0..7)
    const int p    = lane & 15;
    const int g    = lane >> 4;

    f32x4 acc[2][2] = {};                 // [Mtile][colhalf]

    #pragma unroll
    for (int s = 0; s < 18; s++) {
        const int tap = s >> 1;
        const int ky = tap / 3, kx = tap % 3;
        const int c0b = (s & 1) * 64;     // channel-half byte offset
        const __hip_bfloat16* wp = wlds + (size_t)s * 1024 + g * 128 + p * 8;
        bf16x8 a0 = *(const bf16x8*)(wp);
        bf16x8 a1 = *(const bf16x8*)(wp + 512);
        const int srow = wid + ky;
        #pragma unroll
        for (int nf = 0; nf < 2; nf++) {
            int scol = nf * 16 + p + kx;
            int off = (srow * SCc + scol) * 128 + ((c0b + g * 16) ^ ((scol & 7) << 4));
            bf16x8 bv = *(const bf16x8*)(smem + off);
            acc[0][nf] = __builtin_amdgcn_mfma_f32_16x16x32_bf16(a0, bv, acc[0][nf], 0, 0, 0);
            acc[1][nf] = __builtin_amdgcn_mfma_f32_16x16x32_bf16(a1, bv, acc[1][nf], 0, 0, 0);
        }
    }
    __syncthreads();

    // ---- spill: cbuf[ch][px], px = wid*32 + nf*16 + p (0..255) ----
    float* cbuf = (float*)smem;
    #pragma unroll
    for (int mt = 0; mt < 2; mt++) {
        int ch = mt * 16 + g * 4;
        if (ch < 24) {
            #pragma unroll
            for (int nf = 0; nf < 2; nf++) {
                int px = wid * 32 + nf * 16 + p;
                #pragma unroll
                for (int r = 0; r < 4; r++)
                    cbuf[(size_t)(ch + r) * CBS2 + px] = acc[mt][nf][r];
            }
        }
    }
    __syncthreads();

    // ---- pair-split epilogue: thread pair (2i,2i+1) shares pixel i (0..255) ----
    {
        const int pxid = tid >> 1;        // 0..255
        const int sub = tid & 1;          // 0: taps j=0..3, k=0..4, fb0; 1: j=4..7, k=5..8
        const int h = h0 + (pxid >> 5);
        const int w = w0 + (pxid & 31);
        const float scale = aff_scale[0] + 1e-8f;
        const float* confb = confp + (size_t)b * PPLANE;

        float dyv[4], dxv[4], av[4];
        float part = 0.f;
        #pragma unroll
        for (int jj = 0; jj < 4; jj++) {
            int j = sub * 4 + jj;
            float dy = cbuf[(size_t)j * CBS2 + pxid] + conv_b[j];
            float dx = cbuf[(size_t)(8 + j) * CBS2 + pxid] + conv_b[8 + j];
            float a = tanhf(cbuf[(size_t)(16 + j) * CBS2 + pxid] + conv_b[16 + j]) / scale;
            float conf = bilin_pad(confb, (float)h + dy, (float)w + dx);
            a *= conf;
            dyv[jj] = dy; dxv[jj] = dx; av[jj] = a;
            part += fabsf(a);
        }
        float ssum = part + __shfl_xor(part, 1);
        float s = fmaxf(ssum + 1e-4f, 1.0f);
        float inv_s = 1.0f / s;
        float sp = 0.f;
        #pragma unroll
        for (int jj = 0; jj < 4; jj++) { av[jj] *= inv_s; sp += av[jj]; }
        float suma = sp + __shfl_xor(sp, 1);

        const int hw = h * W_ + w;
        auto store_k = [&](int k, float dy, float dx, float a) {
            out_offset[((size_t)(b * 18 + 2 * k) * H_) * W_ + hw] = dy;
            out_offset[((size_t)(b * 18 + 2 * k + 1) * H_) * W_ + hw] = dx;
            out_aff9[((size_t)(b * 9 + k) * H_) * W_ + hw] = a;
            __hip_bfloat16 hy = __float2bfloat16(dy);
            __hip_bfloat16 hx = __float2bfloat16(dx);
            __hip_bfloat16 ha = __float2bfloat16(a);
            unsigned uy = *(ushort*)&hy, ux = *(ushort*)&hx;
            offb[((size_t)(b * 9 + k) * H_) * W_ + hw] = uy | (ux << 16);
            affb[((size_t)(b * 9 + k) * H_) * W_ + hw] = *(ushort*)&ha;
        };
        if (sub == 0) {
            #pragma unroll
            for (int jj = 0; jj < 4; jj++)
                store_k(jj, dyv[jj], dxv[jj], av[jj]);           // k=0..3 (j=k)
            store_k(4, 0.f, 0.f, 1.0f - suma);                    // center
            const size_t pix = (size_t)b * H_ * W_ + hw;
            float ff = feat_fix[pix];
            float fi = feat_init[pix];
            float m = (ff > 0.f) ? 1.f : 0.f;
            fbp0[(size_t)b * PPLANE + (size_t)(h + 2) * WPAD + (w + 2)] =
                (1.f - m) * fi + m * ff;
        } else {
            #pragma unroll
            for (int jj = 0; jj < 4; jj++)
                store_k(5 + jj, dyv[jj], dxv[jj], av[jj]);       // k=5..8 (j=k-1)
        }
    }
}

// Propagation step, 2 pixels per thread, padded fb input, branchless gathers.
// Center tap (k=4) has dy=dx=0 by construction -> exact direct read, no offb load.
__global__ __launch_bounds__(256) void prop_packed_kernel(
    const float* __restrict__ fbp_in, const unsigned* __restrict__ offb,
    const ushort* __restrict__ affb, const float* __restrict__ feat_fix,
    float* __restrict__ out, int do_blend, int out_padded)
{
    const int tpx = blockIdx.x * 256 + threadIdx.x;
    const int n2 = (B_ * H_ * W_) / 2;
    if (tpx >= n2) return;
    const int idx = tpx * 2;
    const int w = idx % W_;
    const int h = (idx / W_) % H_;
    const int b = idx / (W_ * H_);
    const float* fbb = fbp_in + (size_t)b * PPLANE;
    const int hw = h * W_ + w;

    float sum0 = 0.f, sum1 = 0.f;
    #pragma unroll
    for (int k = 0; k < 9; k++) {
        const size_t pb = ((size_t)(b * 9 + k) * H_) * W_ + hw;
        unsigned ua = *(const unsigned*)(affb + pb);
        float a0  = __uint_as_float(ua << 16);
        float a1  = __uint_as_float(ua & 0xFFFF0000u);
        if (k == 4) {
            const float* c = fbb + (size_t)(h + 2) * WPAD + (w + 2);
            sum0 += a0 * c[0];
            sum1 += a1 * c[1];
        } else {
            uint2 uo = *(const uint2*)(offb + pb);
            float yb = (float)h + (float)(k / 3 - 1);
            float xb = (float)w + (float)(k % 3 - 1);
            float dy0 = __uint_as_float(uo.x << 16);
            float dx0 = __uint_as_float(uo.x & 0xFFFF0000u);
            sum0 += a0 * bilin_pad(fbb, yb + dy0, xb + dx0);
            float dy1 = __uint_as_float(uo.y << 16);
            float dx1 = __uint_as_float(uo.y & 0xFFFF0000u);
            sum1 += a1 * bilin_pad(fbb, yb + dy1, xb + 1.0f + dx1);
        }
    }
    if (do_blend) {
        float2 ff = *(const float2*)(feat_fix + idx);
        if (ff.x > 0.f) sum0 = ff.x;
        if (ff.y > 0.f) sum1 = ff.y;
    }
    if (out_padded) {
        float* o = out + (size_t)b * PPLANE + (size_t)(h + 2) * WPAD + (w + 2);
        *(float2*)o = make_float2(sum0, sum1);
    } else {
        *(float2*)(out + idx) = make_float2(sum0, sum1);
    }
}

// ---------------- R5 fallback path (used only if ws_size too small) ----------------
__global__ __launch_bounds__(256, 8) void conv_mfma_r5(
    const float* __restrict__ guidance, const __hip_bfloat16* __restrict__ wfrag,
    const float* __restrict__ conv_b, const float* __restrict__ confidence,
    const float* __restrict__ feat_init, const float* __restrict__ feat_fix,
    const float* __restrict__ aff_scale,
    float* __restrict__ out_offset, float* __restrict__ out_aff9,
    float* __restrict__ fb0)
{
    __shared__ __align__(16) __hip_bfloat16 gl[R5SR * R5SC * R5CPAD];
    const int tid = threadIdx.x;
    int lin = (blockIdx.x & 7) * (R5NBLK / 8) + (blockIdx.x >> 3);
    const int r0 = lin % R5NHT;
    const int rest = lin / R5NHT;
    const int wt = rest % R5NWT;
    const int b  = rest / R5NWT;
    const int h0 = r0 * R5TH;
    const int w0 = wt * R5TC;
    {
        auto stage_one = [&](int i) {
            int col = i % R5SC;
            int rest2 = i / R5SC;
            int kr = rest2 % R5SR;
            int c4 = rest2 / R5SR;
            int gh = h0 - 1 + kr;
            int gw = w0 - 2 + col;
            bool vok = ((unsigned)gh < (unsigned)H_) & ((unsigned)gw < (unsigned)W_);
            union { unsigned long long u; __hip_bfloat16 hv[4]; } pk;
            const float* src = guidance + (((size_t)b * CG_ + c4 * 4) * H_ + gh) * W_ + gw;
            #pragma unroll
            for (int j = 0; j < 4; j++) {
                float v = vok ? src[(size_t)j * H_ * W_] : 0.f;
                pk.hv[j] = __float2bfloat16(v);
            }
            *(unsigned long long*)&gl[(size_t)(kr * R5SC + col) * R5CPAD + c4 * 4] = pk.u;
        };
        #pragma unroll
        for (int it = 0; it < 7; it++) stage_one(tid + it * 256);
        if (tid < R5SR * R5SC * 16 - 7 * 256) stage_one(tid + 7 * 256);
    }
    __syncthreads();
    const int lane = tid & 63;
    const int wid  = tid >> 6;
    const int p    = lane & 15;
    const int g    = lane >> 4;
    f32x4 acc[2] = {};
    #pragma unroll
    for (int s = 0; s < 18; s++) {
        const int tap = s >> 1;
        const int ky = tap / 3, kx = tap % 3;
        const int c0 = (s & 1) * 32;
        const __hip_bfloat16* wp = wfrag + (size_t)s * 1024 + g * 128 + p * 8;
        bf16x8 a0 = *(const bf16x8*)(wp);
        bf16x8 a1 = *(const bf16x8*)(wp + 512);
        int cb = p + kx + 1;
        bf16x8 b0 = *(const bf16x8*)(gl + (size_t)((wid + ky) * R5SC + cb) * R5CPAD + c0 + g * 8);
        acc[0] = __builtin_amdgcn_mfma_f32_16x16x32_bf16(a0, b0, acc[0], 0, 0, 0);
        acc[1] = __builtin_amdgcn_mfma_f32_16x16x32_bf16(a1, b0, acc[1], 0, 0, 0);
    }
    __syncthreads();
    float* cbuf = (float*)gl;
    #pragma unroll
    for (int mt = 0; mt < 2; mt++) {
        int ch = mt * 16 + g * 4;
        if (ch < 24) {
            int px = wid * 16 + p;
            #pragma unroll
            for (int r = 0; r < 4; r++)
                cbuf[(size_t)(ch + r) * R5CBS + px] = acc[mt][r];
        }
    }
    __syncthreads();
    if (tid < R5TH * R5TC) {
        const int h = h0 + (tid >> 4);
        const int w = w0 + (tid & 15);
        float a24[24];
        #pragma unroll
        for (int ch = 0; ch < 24; ch++)
            a24[ch] = cbuf[(size_t)ch * R5CBS + tid] + conv_b[ch];
        prep_epilogue(a24, b, h, w, confidence, feat_init, feat_fix,
                      aff_scale[0] + 1e-8f, out_offset, out_aff9, fb0,
                      (unsigned*)nullptr, (ushort*)nullptr);
    }
}

__global__ __launch_bounds__(256) void prop_f32_kernel(
    const float* __restrict__ fb_in, const float* __restrict__ offset,
    const float* __restrict__ aff9, const float* __restrict__ feat_fix,
    float* __restrict__ out, int do_blend)
{
    const int idx = blockIdx.x * 256 + threadIdx.x;
    const int n = B_ * H_ * W_;
    if (idx >= n) return;
    const int w = idx % W_;
    const int h = (idx / W_) % H_;
    const int b = idx / (W_ * H_);
    const float* fbb = fb_in + (size_t)b * H_ * W_;
    const int hw = h * W_ + w;
    float sum = 0.f;
    #pragma unroll
    for (int k = 0; k < 9; k++) {
        float dy = offset[((size_t)(b * 18 + 2 * k) * H_) * W_ + hw];
        float dx = offset[((size_t)(b * 18 + 2 * k + 1) * H_) * W_ + hw];
        float a  = aff9[((size_t)(b * 9 + k) * H_) * W_ + hw];
        float y = (float)h + (float)(k / 3 - 1) + dy;
        float x = (float)w + (float)(k % 3 - 1) + dx;
        sum += a * bilin_zero(fbb, y, x);
    }
    if (do_blend) {
        float ff = feat_fix[idx];
        float m = (ff > 0.f) ? 1.f : 0.f;
        sum = (1.f - m) * sum + m * ff;
    }
    out[idx] = sum;
}

extern "C" void kernel_launch(void* const* d_in, const int* in_sizes, int n_in,
                              void* d_out, int out_size, void* d_ws, size_t ws_size,
                              hipStream_t stream) {
    const float* feat_init  = (const float*)d_in[0];
    const float* guidance   = (const float*)d_in[1];
    const float* confidence = (const float*)d_in[2];
    const float* feat_fix   = (const float*)d_in[3];
    const float* conv_w     = (const float*)d_in[4];
    const float* conv_b     = (const float*)d_in[5];
    const float* aff_scale  = (const float*)d_in[6];

    float* out_feat = (float*)d_out;
    const size_t P1 = (size_t)B_ * H_ * W_;
    float* out_offset = out_feat + P1;
    float* out_aff9   = out_offset + 18 * P1;

    char* ws = (char*)d_ws;
    float* fb0 = (float*)ws;                                   ws += P1 * 4;   // fallback only
    float* fb1 = (float*)ws;                                   ws += P1 * 4;   // fallback only
    __hip_bfloat16* wfrag = (__hip_bfloat16*)ws;               ws += 32 * NUMK * 2;
    unsigned* offb = (unsigned*)ws;                            ws += 9 * P1 * 4;
    ushort* affb = (ushort*)ws;                                ws += 9 * P1 * 2;
    __hip_bfloat16* gbf = (__hip_bfloat16*)ws;                 ws += (size_t)B_ * HP * WP * 64 * 2;
    float* fbp0 = (float*)ws;                                  ws += B_ * PPLANE * 4;
    float* fbp1 = (float*)ws;                                  ws += B_ * PPLANE * 4;
    float* confp = (float*)ws;                                 ws += B_ * PPLANE * 4;
    const size_t need = (size_t)(ws - (char*)d_ws);

    repack_w_kernel<<<(32 * NUMK + 255) / 256, 256, 0, stream>>>(conv_w, wfrag);

    const int n = (int)P1;

    if (ws_size >= need) {
        const int ni = BORD_TOTAL + (int)(B_ * PPLANE);
        init_pads_kernel<<<(ni + 255) / 256, 256, 0, stream>>>(confidence, fbp0);
        transpose_kernel<<<dim3(19, HP, B_), 256, 0, stream>>>(guidance, gbf);
        conv_lds_kernel<<<NBLK3, 512, 0, stream>>>(
            gbf, wfrag, conv_b, confp, feat_init, feat_fix, aff_scale,
            out_offset, out_aff9, fbp0, offb, affb);
        const int p2blocks = (n / 2 + 255) / 256;
        float* pbufs[2] = {fbp0, fbp1};
        for (int it = 0; it < 6; it++) {
            const float* in = pbufs[it & 1];
            float* o = (it == 5) ? out_feat : pbufs[(it + 1) & 1];
            prop_packed_kernel<<<p2blocks, 256, 0, stream>>>(
                in, offb, affb, feat_fix, o, (it < 5) ? 1 : 0, (it < 5) ? 1 : 0);
        }
    } else {
        const int pblocks = (n + 255) / 256;
        float* bufs[2] = {fb0, fb1};
        conv_mfma_r5<<<R5NBLK, 256, 0, stream>>>(
            guidance, wfrag, conv_b, confidence, feat_init, feat_fix, aff_scale,
            out_offset, out_aff9, fb0);
        for (int it = 0; it < 6; it++) {
            const float* in = bufs[it & 1];
            float* o = (it == 5) ? out_feat : bufs[(it + 1) & 1];
            prop_f32_kernel<<<pblocks, 256, 0, stream>>>(
                in, out_offset, out_aff9, feat_fix, o, (it < 5) ? 1 : 0);
        }
    }
}